// Round 23
// baseline (221.902 us; speedup 1.0000x reference)
//
#include <hip/hip_runtime.h>

#define DD 48
#define TT 512
#define BB 512
#define PF 8
#define AWS_STRIDE 64
#define AWS_BYTES ((size_t)BB * TT * AWS_STRIDE * 4)   // 67,108,864
#define WS_NEED AWS_BYTES

__device__ __forceinline__ float readlane_f(float v, int lane) {
  return __int_as_float(__builtin_amdgcn_readlane(__float_as_int(v), lane));
}
__device__ __forceinline__ float max3f(float a, float b, float c) {
  return fmaxf(fmaxf(a, b), c);
}

// pure value max over 48 (VCC-free, fuses to v_max3_f32)
__device__ __forceinline__ float vmax48(const float* s) {
  float m1[16];
#pragma unroll
  for (int k = 0; k < 16; ++k) m1[k] = max3f(s[3 * k], s[3 * k + 1], s[3 * k + 2]);
  float m2[6];
#pragma unroll
  for (int k = 0; k < 5; ++k) m2[k] = max3f(m1[3 * k], m1[3 * k + 1], m1[3 * k + 2]);
  m2[5] = m1[15];
  return fmaxf(max3f(m2[0], m2[1], m2[2]), max3f(m2[3], m2[4], m2[5]));
}

// argmax with first-index ties (strict > moves right) — once per batch
__device__ __forceinline__ int argidx48(const float* s) {
  float v1[24]; int x1[24];
#pragma unroll
  for (int k = 0; k < 24; ++k) {
    float l = s[2 * k], r = s[2 * k + 1];
    v1[k] = fmaxf(l, r); x1[k] = (r > l) ? 2 * k + 1 : 2 * k;
  }
  float v2[12]; int x2[12];
#pragma unroll
  for (int k = 0; k < 12; ++k) {
    float l = v1[2 * k], r = v1[2 * k + 1];
    v2[k] = fmaxf(l, r); x2[k] = (r > l) ? x1[2 * k + 1] : x1[2 * k];
  }
  float v3[6]; int x3[6];
#pragma unroll
  for (int k = 0; k < 6; ++k) {
    float l = v2[2 * k], r = v2[2 * k + 1];
    v3[k] = fmaxf(l, r); x3[k] = (r > l) ? x2[2 * k + 1] : x2[2 * k];
  }
  float v4[3]; int x4[3];
#pragma unroll
  for (int k = 0; k < 3; ++k) {
    float l = v3[2 * k], r = v3[2 * k + 1];
    v4[k] = fmaxf(l, r); x4[k] = (r > l) ? x3[2 * k + 1] : x3[2 * k];
  }
  float vm = fmaxf(v4[0], v4[1]);
  int xm = (v4[1] > v4[0]) ? x4[1] : x4[0];
  return (v4[2] > vm) ? x4[2] : xm;
}

// ---- single kernel: fwd (stores best rows) + exec-free equality backtrack ----
__global__ __launch_bounds__(64, 1) void crf_all(const float* __restrict__ logits,
                                                 const int* __restrict__ lens,
                                                 const float* __restrict__ trans,
                                                 float* __restrict__ aws,
                                                 int* __restrict__ out) {
  const int b = blockIdx.x;
  const int j = threadIdx.x;
  const int jj = j < DD ? j : DD - 1;

  __shared__ float Tt[DD * 64]; // Tt[tag*64 + i] = trans[i][tag]; i>=48 -> -1e30

  // one-time transposed T into LDS (single wave: in-order DS, no barrier)
  for (int tg = 0; tg < DD; ++tg)
    Tt[(tg << 6) | j] = (j < DD) ? trans[(size_t)j * DD + tg] : -1e30f;

  float tcol[DD];
#pragma unroll
  for (int i = 0; i < DD; ++i) tcol[i] = trans[i * DD + jj];

  const float* lg = logits + (size_t)b * TT * DD;
  const int L = lens[b];

  float alpha = lg[jj];
  float* awsb = aws + (size_t)b * TT * AWS_STRIDE;
  awsb[j] = alpha; // row 0 = alpha0

  float e0 = lg[1 * DD + jj], e1 = lg[2 * DD + jj],
        e2 = lg[3 * DD + jj], e3 = lg[4 * DD + jj],
        e4 = lg[5 * DD + jj], e5 = lg[6 * DD + jj],
        e6 = lg[7 * DD + jj], e7 = lg[8 * DD + jj];

  // fwd step (R16 form) — stores BEST row (pre-emit max), not alpha
#define STEP(EV)                                                    \
  {                                                                 \
    float a_[DD];                                                   \
    _Pragma("unroll")                                               \
    for (int i = 0; i < DD; ++i) a_[i] = readlane_f(alpha, i);      \
    float s_[DD];                                                   \
    _Pragma("unroll")                                               \
    for (int i = 0; i < DD; ++i) s_[i] = a_[i] + tcol[i];           \
    float best = vmax48(s_);                                        \
    awsb[(t << 6) | j] = best;                                      \
    alpha = best + (EV);                                            \
  }
#define RELOAD(ES)                                 \
  {                                                \
    int r = t + PF; r = r > TT - 1 ? TT - 1 : r;   \
    ES = lg[r * DD + jj];                          \
  }

  int t = 1;
  while (t < L) {
    STEP(e0); RELOAD(e0); ++t; if (t >= L) break;
    STEP(e1); RELOAD(e1); ++t; if (t >= L) break;
    STEP(e2); RELOAD(e2); ++t; if (t >= L) break;
    STEP(e3); RELOAD(e3); ++t; if (t >= L) break;
    STEP(e4); RELOAD(e4); ++t; if (t >= L) break;
    STEP(e5); RELOAD(e5); ++t; if (t >= L) break;
    STEP(e6); RELOAD(e6); ++t; if (t >= L) break;
    STEP(e7); RELOAD(e7); ++t;
  }
#undef STEP
#undef RELOAD

  // ---- bp-free backtrack, exec-free outputs ----
  asm volatile("s_waitcnt vmcnt(0)" ::: "memory"); // best-row stores visible

  int* ob = out + (size_t)b * TT;
  int tag;
  {
    float af[DD];
#pragma unroll
    for (int i = 0; i < DD; ++i) af[i] = readlane_f(alpha, i);
    tag = argidx48(af);
  }
  const int btag = tag;
  if (j == 0) ob[L - 1] = btag; // covers L-1 when its group is never flushed

  // tag-history collection: lane (o&63) holds tag for out index o; full-wave
  // flush at each o multiple of 64. Seed btag if top flush group contains L-1.
  int th = 0;
  {
    const int gtop = (L - 2) >> 6;           // top flushed group (L>=2); -1 if L==1
    if (((L - 1) >> 6) == gtop)
      th = (j == ((L - 1) & 63)) ? btag : 0;
  }

  // descending 8-slot ring: BR=best row (row0=alpha0), ER=logits row
  float br0, br1, br2, br3, br4, br5, br6, br7;
  float er0, er1, er2, er3, er4, er5, er6, er7;
#define LROW(BR, ER, R)                              \
  {                                                  \
    int r = (R) < 0 ? 0 : (R);                       \
    BR = awsb[(r << 6) | j];                         \
    ER = lg[r * DD + jj];                            \
  }
  LROW(br0, er0, L - 1) LROW(br1, er1, L - 2) LROW(br2, er2, L - 3)
  LROW(br3, er3, L - 4) LROW(br4, er4, L - 5) LROW(br5, er5, L - 6)
  LROW(br6, er6, L - 7) LROW(br7, er7, L - 8)

  // one backtrack step at time TT_: uses BRa (row tt), BRb/ERb (row tt-1)
#define BSTEP(BRa, BRb, ERb, TT_)                              \
  {                                                            \
    const int tt = (TT_);                                      \
    float aprev = (tt == 1) ? (BRb) : ((BRb) + (ERb));         \
    float target = readlane_f((BRa), tag);                     \
    float tc = Tt[(tag << 6) | j];                             \
    unsigned long long m = __ballot(aprev + tc == target);     \
    int nt = __ffsll((long long)m);                            \
    tag = nt ? nt - 1 : 0;                                     \
    const int o = tt - 1;                                      \
    th = (j == (o & 63)) ? tag : th;                           \
    if ((o & 63) == 0) ob[(o & ~63) + j] = th;                 \
  }

  for (int tb = L - 1; tb >= 1; tb -= 8) {
    if (tb - 0 >= 1) { BSTEP(br0, br1, er1, tb - 0); LROW(br0, er0, tb - 8); }
    if (tb - 1 >= 1) { BSTEP(br1, br2, er2, tb - 1); LROW(br1, er1, tb - 9); }
    if (tb - 2 >= 1) { BSTEP(br2, br3, er3, tb - 2); LROW(br2, er2, tb - 10); }
    if (tb - 3 >= 1) { BSTEP(br3, br4, er4, tb - 3); LROW(br3, er3, tb - 11); }
    if (tb - 4 >= 1) { BSTEP(br4, br5, er5, tb - 4); LROW(br4, er4, tb - 12); }
    if (tb - 5 >= 1) { BSTEP(br5, br6, er6, tb - 5); LROW(br5, er5, tb - 13); }
    if (tb - 6 >= 1) { BSTEP(br6, br7, er7, tb - 6); LROW(br6, er6, tb - 14); }
    if (tb - 7 >= 1) { BSTEP(br7, br0, er0, tb - 7); LROW(br7, er7, tb - 15); }
  }
#undef BSTEP
#undef LROW

  // zero the padded tail t >= L (after flushes: overwrites top-group garbage)
  for (int tt = L + j; tt < TT; tt += 64) ob[tt] = 0;
}

// ---- fallback (ws too small): proven single-kernel ----
__global__ __launch_bounds__(64, 1) void crf_fallback(const float* __restrict__ logits,
                                                      const int* __restrict__ lens,
                                                      const float* __restrict__ trans,
                                                      int* __restrict__ out) {
  const int b = blockIdx.x;
  const int j = threadIdx.x;
  const int jj = j < DD ? j : DD - 1;
  __shared__ unsigned char bp[TT * 64];

  float tcol[DD];
#pragma unroll
  for (int i = 0; i < DD; ++i) tcol[i] = trans[i * DD + jj];
  const float* lg = logits + (size_t)b * TT * DD;
  const int L = lens[b];
  float alpha = lg[jj];

  float e0 = lg[1 * DD + jj], e1 = lg[2 * DD + jj],
        e2 = lg[3 * DD + jj], e3 = lg[4 * DD + jj],
        e4 = lg[5 * DD + jj], e5 = lg[6 * DD + jj],
        e6 = lg[7 * DD + jj], e7 = lg[8 * DD + jj];

#define STEP(EV)                                                         \
  {                                                                      \
    float s_[DD];                                                        \
    _Pragma("unroll")                                                    \
    for (int i = 0; i < DD; ++i) s_[i] = readlane_f(alpha, i) + tcol[i]; \
    float best = vmax48(s_);                                             \
    int idx = argidx48(s_);                                              \
    alpha = best + (EV);                                                 \
    bp[t * 64 + j] = (unsigned char)idx;                                 \
  }
#define RELOAD(ES)                                 \
  {                                                \
    int r = t + PF; r = r > TT - 1 ? TT - 1 : r;   \
    ES = lg[r * DD + jj];                          \
  }
  int t = 1;
  while (t < L) {
    STEP(e0); RELOAD(e0); ++t; if (t >= L) break;
    STEP(e1); RELOAD(e1); ++t; if (t >= L) break;
    STEP(e2); RELOAD(e2); ++t; if (t >= L) break;
    STEP(e3); RELOAD(e3); ++t; if (t >= L) break;
    STEP(e4); RELOAD(e4); ++t; if (t >= L) break;
    STEP(e5); RELOAD(e5); ++t; if (t >= L) break;
    STEP(e6); RELOAD(e6); ++t; if (t >= L) break;
    STEP(e7); RELOAD(e7); ++t;
  }
#undef STEP
#undef RELOAD
  __syncthreads();

  float af[DD];
#pragma unroll
  for (int i = 0; i < DD; ++i) af[i] = readlane_f(alpha, i);
  int btag = argidx48(af);
  int* ob = out + (size_t)b * TT;
  if (j == 0) ob[L - 1] = btag;
  int H = j;
  for (int tt = L - 1; tt >= 1; --tt) {
    int v = bp[tt * 64 + jj];
    H = __shfl(v, H, 64);
    if (j == btag) ob[tt - 1] = H;
  }
  for (int tt = L + j; tt < TT; tt += 64) ob[tt] = 0;
}

extern "C" void kernel_launch(void* const* d_in, const int* in_sizes, int n_in,
                              void* d_out, int out_size, void* d_ws, size_t ws_size,
                              hipStream_t stream) {
  const float* logits = (const float*)d_in[0];
  const int* lens     = (const int*)d_in[1];
  const float* trans  = (const float*)d_in[2];
  int* out            = (int*)d_out;
  (void)in_sizes; (void)n_in; (void)out_size;

  if (ws_size >= WS_NEED) {
    float* aws = (float*)d_ws;
    crf_all<<<BB, 64, 0, stream>>>(logits, lens, trans, aws, out);
  } else {
    crf_fallback<<<BB, 64, 0, stream>>>(logits, lens, trans, out);
  }
}

// Round 24
// 205.739 us; speedup vs baseline: 1.0786x; 1.0786x over previous
//
#include <hip/hip_runtime.h>

#define DD 48
#define TT 512
#define BB 512
#define PF 8
#define AWS_STRIDE 64
#define AWS_BYTES ((size_t)BB * TT * AWS_STRIDE * 4)   // 67,108,864
#define WS_NEED AWS_BYTES

__device__ __forceinline__ float readlane_f(float v, int lane) {
  return __int_as_float(__builtin_amdgcn_readlane(__float_as_int(v), lane));
}
__device__ __forceinline__ float max3f(float a, float b, float c) {
  return fmaxf(fmaxf(a, b), c);
}

// pure value max over 48 (VCC-free, fuses to v_max3_f32)
__device__ __forceinline__ float vmax48(const float* s) {
  float m1[16];
#pragma unroll
  for (int k = 0; k < 16; ++k) m1[k] = max3f(s[3 * k], s[3 * k + 1], s[3 * k + 2]);
  float m2[6];
#pragma unroll
  for (int k = 0; k < 5; ++k) m2[k] = max3f(m1[3 * k], m1[3 * k + 1], m1[3 * k + 2]);
  m2[5] = m1[15];
  return fmaxf(max3f(m2[0], m2[1], m2[2]), max3f(m2[3], m2[4], m2[5]));
}

// argmax with first-index ties (strict > moves right) — once per batch
__device__ __forceinline__ int argidx48(const float* s) {
  float v1[24]; int x1[24];
#pragma unroll
  for (int k = 0; k < 24; ++k) {
    float l = s[2 * k], r = s[2 * k + 1];
    v1[k] = fmaxf(l, r); x1[k] = (r > l) ? 2 * k + 1 : 2 * k;
  }
  float v2[12]; int x2[12];
#pragma unroll
  for (int k = 0; k < 12; ++k) {
    float l = v1[2 * k], r = v1[2 * k + 1];
    v2[k] = fmaxf(l, r); x2[k] = (r > l) ? x1[2 * k + 1] : x1[2 * k];
  }
  float v3[6]; int x3[6];
#pragma unroll
  for (int k = 0; k < 6; ++k) {
    float l = v2[2 * k], r = v2[2 * k + 1];
    v3[k] = fmaxf(l, r); x3[k] = (r > l) ? x2[2 * k + 1] : x2[2 * k];
  }
  float v4[3]; int x4[3];
#pragma unroll
  for (int k = 0; k < 3; ++k) {
    float l = v3[2 * k], r = v3[2 * k + 1];
    v4[k] = fmaxf(l, r); x4[k] = (r > l) ? x3[2 * k + 1] : x3[2 * k];
  }
  float vm = fmaxf(v4[0], v4[1]);
  int xm = (v4[1] > v4[0]) ? x4[1] : x4[0];
  return (v4[2] > vm) ? x4[2] : xm;
}

// ---- single kernel: fwd (stores best rows) + bp-free equality backtrack ----
__global__ __launch_bounds__(64, 1) void crf_all(const float* __restrict__ logits,
                                                 const int* __restrict__ lens,
                                                 const float* __restrict__ trans,
                                                 float* __restrict__ aws,
                                                 int* __restrict__ out) {
  const int b = blockIdx.x;
  const int j = threadIdx.x;
  const int jj = j < DD ? j : DD - 1;

  __shared__ float Tt[DD * 64]; // Tt[tag*64 + i] = trans[i][tag]; i>=48 -> -1e30

  // one-time transposed T into LDS (single wave: in-order DS, no barrier)
  for (int tg = 0; tg < DD; ++tg)
    Tt[(tg << 6) | j] = (j < DD) ? trans[(size_t)j * DD + tg] : -1e30f;

  float tcol[DD];
#pragma unroll
  for (int i = 0; i < DD; ++i) tcol[i] = trans[i * DD + jj];

  const float* lg = logits + (size_t)b * TT * DD;
  const int L = lens[b];

  float alpha = lg[jj];
  float* awsb = aws + (size_t)b * TT * AWS_STRIDE;
  awsb[j] = alpha; // row 0 = alpha0

  float e0 = lg[1 * DD + jj], e1 = lg[2 * DD + jj],
        e2 = lg[3 * DD + jj], e3 = lg[4 * DD + jj],
        e4 = lg[5 * DD + jj], e5 = lg[6 * DD + jj],
        e6 = lg[7 * DD + jj], e7 = lg[8 * DD + jj];

  // fwd step (R16 form) — stores BEST row (pre-emit max), not alpha
#define STEP(EV)                                                    \
  {                                                                 \
    float a_[DD];                                                   \
    _Pragma("unroll")                                               \
    for (int i = 0; i < DD; ++i) a_[i] = readlane_f(alpha, i);      \
    float s_[DD];                                                   \
    _Pragma("unroll")                                               \
    for (int i = 0; i < DD; ++i) s_[i] = a_[i] + tcol[i];           \
    float best = vmax48(s_);                                        \
    awsb[(t << 6) | j] = best;                                      \
    alpha = best + (EV);                                            \
  }
#define RELOAD(ES)                                 \
  {                                                \
    int r = t + PF; r = r > TT - 1 ? TT - 1 : r;   \
    ES = lg[r * DD + jj];                          \
  }

  int t = 1;
  while (t < L) {
    STEP(e0); RELOAD(e0); ++t; if (t >= L) break;
    STEP(e1); RELOAD(e1); ++t; if (t >= L) break;
    STEP(e2); RELOAD(e2); ++t; if (t >= L) break;
    STEP(e3); RELOAD(e3); ++t; if (t >= L) break;
    STEP(e4); RELOAD(e4); ++t; if (t >= L) break;
    STEP(e5); RELOAD(e5); ++t; if (t >= L) break;
    STEP(e6); RELOAD(e6); ++t; if (t >= L) break;
    STEP(e7); RELOAD(e7); ++t;
  }
#undef STEP
#undef RELOAD

  // ---- bp-free backtrack ----
  asm volatile("s_waitcnt vmcnt(0)" ::: "memory"); // best-row stores visible

  int* ob = out + (size_t)b * TT;
  int tag;
  {
    float af[DD];
#pragma unroll
    for (int i = 0; i < DD; ++i) af[i] = readlane_f(alpha, i);
    tag = argidx48(af);
  }
  if (j == 0) ob[L - 1] = tag;

  // descending 8-slot ring: BR = best row r; AP = alpha_r (= BR + e_r, r>=1;
  // row 0 stores alpha0 directly so AP=BR). AP precomputed at load (off-chain).
  float br0, br1, br2, br3, br4, br5, br6, br7;
  float ap0, ap1, ap2, ap3, ap4, ap5, ap6, ap7;
#define LROW(BR, AP, R)                              \
  {                                                  \
    int r = (R) < 0 ? 0 : (R);                       \
    BR = awsb[(r << 6) | j];                         \
    float er = lg[r * DD + jj];                      \
    AP = r ? (BR + er) : BR;                         \
  }
  LROW(br0, ap0, L - 1) LROW(br1, ap1, L - 2) LROW(br2, ap2, L - 3)
  LROW(br3, ap3, L - 4) LROW(br4, ap4, L - 5) LROW(br5, ap5, L - 6)
  LROW(br6, ap6, L - 7) LROW(br7, ap7, L - 8)

  // one backtrack step at time TT_: BRa = best row tt (target), APb = alpha row tt-1
#define BSTEP(BRa, APb, TT_)                                   \
  {                                                            \
    const int tt = (TT_);                                      \
    float target = readlane_f((BRa), tag);                     \
    float tc = Tt[(tag << 6) | j];                             \
    unsigned long long m = __ballot((APb) + tc == target);     \
    int nt = __ffsll((long long)m);                            \
    tag = nt ? nt - 1 : 0;                                     \
    if (j == 0) ob[tt - 1] = tag;                              \
  }

  int tb = L - 1;
  // main: guard-free blocks of 8 (all steps tb..tb-7 >= 1)
  while (tb >= 8) {
    BSTEP(br0, ap1, tb - 0); LROW(br0, ap0, tb - 8);
    BSTEP(br1, ap2, tb - 1); LROW(br1, ap1, tb - 9);
    BSTEP(br2, ap3, tb - 2); LROW(br2, ap2, tb - 10);
    BSTEP(br3, ap4, tb - 3); LROW(br3, ap3, tb - 11);
    BSTEP(br4, ap5, tb - 4); LROW(br4, ap4, tb - 12);
    BSTEP(br5, ap6, tb - 5); LROW(br5, ap5, tb - 13);
    BSTEP(br6, ap7, tb - 6); LROW(br6, ap6, tb - 14);
    BSTEP(br7, ap0, tb - 7); LROW(br7, ap7, tb - 15);
    tb -= 8;
  }
  // tail: tb in [0,7]; slot u holds row tb-u, ap slot u+1 holds row tb-u-1
  if (tb >= 1) { BSTEP(br0, ap1, tb - 0); }
  if (tb >= 2) { BSTEP(br1, ap2, tb - 1); }
  if (tb >= 3) { BSTEP(br2, ap3, tb - 2); }
  if (tb >= 4) { BSTEP(br3, ap4, tb - 3); }
  if (tb >= 5) { BSTEP(br4, ap5, tb - 4); }
  if (tb >= 6) { BSTEP(br5, ap6, tb - 5); }
  if (tb >= 7) { BSTEP(br6, ap7, tb - 6); }
#undef BSTEP
#undef LROW

  // zero the padded tail t >= L
  for (int tt = L + j; tt < TT; tt += 64) ob[tt] = 0;
}

// ---- fallback (ws too small): proven single-kernel ----
__global__ __launch_bounds__(64, 1) void crf_fallback(const float* __restrict__ logits,
                                                      const int* __restrict__ lens,
                                                      const float* __restrict__ trans,
                                                      int* __restrict__ out) {
  const int b = blockIdx.x;
  const int j = threadIdx.x;
  const int jj = j < DD ? j : DD - 1;
  __shared__ unsigned char bp[TT * 64];

  float tcol[DD];
#pragma unroll
  for (int i = 0; i < DD; ++i) tcol[i] = trans[i * DD + jj];
  const float* lg = logits + (size_t)b * TT * DD;
  const int L = lens[b];
  float alpha = lg[jj];

  float e0 = lg[1 * DD + jj], e1 = lg[2 * DD + jj],
        e2 = lg[3 * DD + jj], e3 = lg[4 * DD + jj],
        e4 = lg[5 * DD + jj], e5 = lg[6 * DD + jj],
        e6 = lg[7 * DD + jj], e7 = lg[8 * DD + jj];

#define STEP(EV)                                                         \
  {                                                                      \
    float s_[DD];                                                        \
    _Pragma("unroll")                                                    \
    for (int i = 0; i < DD; ++i) s_[i] = readlane_f(alpha, i) + tcol[i]; \
    float best = vmax48(s_);                                             \
    int idx = argidx48(s_);                                              \
    alpha = best + (EV);                                                 \
    bp[t * 64 + j] = (unsigned char)idx;                                 \
  }
#define RELOAD(ES)                                 \
  {                                                \
    int r = t + PF; r = r > TT - 1 ? TT - 1 : r;   \
    ES = lg[r * DD + jj];                          \
  }
  int t = 1;
  while (t < L) {
    STEP(e0); RELOAD(e0); ++t; if (t >= L) break;
    STEP(e1); RELOAD(e1); ++t; if (t >= L) break;
    STEP(e2); RELOAD(e2); ++t; if (t >= L) break;
    STEP(e3); RELOAD(e3); ++t; if (t >= L) break;
    STEP(e4); RELOAD(e4); ++t; if (t >= L) break;
    STEP(e5); RELOAD(e5); ++t; if (t >= L) break;
    STEP(e6); RELOAD(e6); ++t; if (t >= L) break;
    STEP(e7); RELOAD(e7); ++t;
  }
#undef STEP
#undef RELOAD
  __syncthreads();

  float af[DD];
#pragma unroll
  for (int i = 0; i < DD; ++i) af[i] = readlane_f(alpha, i);
  int btag = argidx48(af);
  int* ob = out + (size_t)b * TT;
  if (j == 0) ob[L - 1] = btag;
  int H = j;
  for (int tt = L - 1; tt >= 1; --tt) {
    int v = bp[tt * 64 + jj];
    H = __shfl(v, H, 64);
    if (j == btag) ob[tt - 1] = H;
  }
  for (int tt = L + j; tt < TT; tt += 64) ob[tt] = 0;
}

extern "C" void kernel_launch(void* const* d_in, const int* in_sizes, int n_in,
                              void* d_out, int out_size, void* d_ws, size_t ws_size,
                              hipStream_t stream) {
  const float* logits = (const float*)d_in[0];
  const int* lens     = (const int*)d_in[1];
  const float* trans  = (const float*)d_in[2];
  int* out            = (int*)d_out;
  (void)in_sizes; (void)n_in; (void)out_size;

  if (ws_size >= WS_NEED) {
    float* aws = (float*)d_ws;
    crf_all<<<BB, 64, 0, stream>>>(logits, lens, trans, aws, out);
  } else {
    crf_fallback<<<BB, 64, 0, stream>>>(logits, lens, trans, out);
  }
}

// Round 25
// 197.741 us; speedup vs baseline: 1.1222x; 1.0404x over previous
//
#include <hip/hip_runtime.h>

#define DD 48
#define TT 512
#define BB 512
#define PF 8
#define AWS_STRIDE 64
#define AWS_BYTES ((size_t)BB * TT * AWS_STRIDE * 4)   // 67,108,864
#define WS_NEED AWS_BYTES

__device__ __forceinline__ float readlane_f(float v, int lane) {
  return __int_as_float(__builtin_amdgcn_readlane(__float_as_int(v), lane));
}
__device__ __forceinline__ float max3f(float a, float b, float c) {
  return fmaxf(fmaxf(a, b), c);
}

// pure value max over 48 (VCC-free, fuses to v_max3_f32)
__device__ __forceinline__ float vmax48(const float* s) {
  float m1[16];
#pragma unroll
  for (int k = 0; k < 16; ++k) m1[k] = max3f(s[3 * k], s[3 * k + 1], s[3 * k + 2]);
  float m2[6];
#pragma unroll
  for (int k = 0; k < 5; ++k) m2[k] = max3f(m1[3 * k], m1[3 * k + 1], m1[3 * k + 2]);
  m2[5] = m1[15];
  return fmaxf(max3f(m2[0], m2[1], m2[2]), max3f(m2[3], m2[4], m2[5]));
}

// argmax with first-index ties (strict > moves right) — once per batch
__device__ __forceinline__ int argidx48(const float* s) {
  float v1[24]; int x1[24];
#pragma unroll
  for (int k = 0; k < 24; ++k) {
    float l = s[2 * k], r = s[2 * k + 1];
    v1[k] = fmaxf(l, r); x1[k] = (r > l) ? 2 * k + 1 : 2 * k;
  }
  float v2[12]; int x2[12];
#pragma unroll
  for (int k = 0; k < 12; ++k) {
    float l = v1[2 * k], r = v1[2 * k + 1];
    v2[k] = fmaxf(l, r); x2[k] = (r > l) ? x1[2 * k + 1] : x1[2 * k];
  }
  float v3[6]; int x3[6];
#pragma unroll
  for (int k = 0; k < 6; ++k) {
    float l = v2[2 * k], r = v2[2 * k + 1];
    v3[k] = fmaxf(l, r); x3[k] = (r > l) ? x2[2 * k + 1] : x2[2 * k];
  }
  float v4[3]; int x4[3];
#pragma unroll
  for (int k = 0; k < 3; ++k) {
    float l = v3[2 * k], r = v3[2 * k + 1];
    v4[k] = fmaxf(l, r); x4[k] = (r > l) ? x3[2 * k + 1] : x3[2 * k];
  }
  float vm = fmaxf(v4[0], v4[1]);
  int xm = (v4[1] > v4[0]) ? x4[1] : x4[0];
  return (v4[2] > vm) ? x4[2] : xm;
}

// ---- single kernel: fwd (stores best rows) + bp-free equality backtrack ----
__global__ __launch_bounds__(64, 1) void crf_all(const float* __restrict__ logits,
                                                 const int* __restrict__ lens,
                                                 const float* __restrict__ trans,
                                                 float* __restrict__ aws,
                                                 int* __restrict__ out) {
  const int b = blockIdx.x;
  const int j = threadIdx.x;
  const int jj = j < DD ? j : DD - 1;

  __shared__ float Tt[DD * 64]; // Tt[tag*64 + i] = trans[i][tag]; i>=48 -> -1e30

  // one-time transposed T into LDS (single wave: in-order DS, no barrier)
  for (int tg = 0; tg < DD; ++tg)
    Tt[(tg << 6) | j] = (j < DD) ? trans[(size_t)j * DD + tg] : -1e30f;

  float tcol[DD];
#pragma unroll
  for (int i = 0; i < DD; ++i) tcol[i] = trans[i * DD + jj];

  const float* lg = logits + (size_t)b * TT * DD;
  const int L = lens[b];

  float alpha = lg[jj];
  float* awsb = aws + (size_t)b * TT * AWS_STRIDE;
  awsb[j] = alpha; // row 0 = alpha0

  float e0 = lg[1 * DD + jj], e1 = lg[2 * DD + jj],
        e2 = lg[3 * DD + jj], e3 = lg[4 * DD + jj],
        e4 = lg[5 * DD + jj], e5 = lg[6 * DD + jj],
        e6 = lg[7 * DD + jj], e7 = lg[8 * DD + jj];

  // fwd step (R16 form) — stores BEST row (pre-emit max), not alpha
#define STEP(EV)                                                    \
  {                                                                 \
    float a_[DD];                                                   \
    _Pragma("unroll")                                               \
    for (int i = 0; i < DD; ++i) a_[i] = readlane_f(alpha, i);      \
    float s_[DD];                                                   \
    _Pragma("unroll")                                               \
    for (int i = 0; i < DD; ++i) s_[i] = a_[i] + tcol[i];           \
    float best = vmax48(s_);                                        \
    awsb[(t << 6) | j] = best;                                      \
    alpha = best + (EV);                                            \
  }
#define RELOAD(ES)                                 \
  {                                                \
    int r = t + PF; r = r > TT - 1 ? TT - 1 : r;   \
    ES = lg[r * DD + jj];                          \
  }

  int t = 1;
  while (t < L) {
    STEP(e0); RELOAD(e0); ++t; if (t >= L) break;
    STEP(e1); RELOAD(e1); ++t; if (t >= L) break;
    STEP(e2); RELOAD(e2); ++t; if (t >= L) break;
    STEP(e3); RELOAD(e3); ++t; if (t >= L) break;
    STEP(e4); RELOAD(e4); ++t; if (t >= L) break;
    STEP(e5); RELOAD(e5); ++t; if (t >= L) break;
    STEP(e6); RELOAD(e6); ++t; if (t >= L) break;
    STEP(e7); RELOAD(e7); ++t;
  }
#undef STEP
#undef RELOAD

  // ---- bp-free backtrack ----
  asm volatile("s_waitcnt vmcnt(0)" ::: "memory"); // best-row stores visible

  int* ob = out + (size_t)b * TT;
  int tag;
  {
    float af[DD];
#pragma unroll
    for (int i = 0; i < DD; ++i) af[i] = readlane_f(alpha, i);
    tag = argidx48(af);
  }
  if (j == 0) ob[L - 1] = tag;

  // descending 16-slot ring: BR = best row r; AP = alpha_r (= BR + e_r for r>=1;
  // row 0 stores alpha0 directly so AP=BR). AP precomputed at load (off-chain).
  float br0, br1, br2, br3, br4, br5, br6, br7,
        br8, br9, br10, br11, br12, br13, br14, br15;
  float ap0, ap1, ap2, ap3, ap4, ap5, ap6, ap7,
        ap8, ap9, ap10, ap11, ap12, ap13, ap14, ap15;
#define LROW(BR, AP, R)                              \
  {                                                  \
    int r = (R) < 0 ? 0 : (R);                       \
    BR = awsb[(r << 6) | j];                         \
    float er = lg[r * DD + jj];                      \
    AP = r ? (BR + er) : BR;                         \
  }
  LROW(br0, ap0, L - 1)   LROW(br1, ap1, L - 2)   LROW(br2, ap2, L - 3)
  LROW(br3, ap3, L - 4)   LROW(br4, ap4, L - 5)   LROW(br5, ap5, L - 6)
  LROW(br6, ap6, L - 7)   LROW(br7, ap7, L - 8)   LROW(br8, ap8, L - 9)
  LROW(br9, ap9, L - 10)  LROW(br10, ap10, L - 11) LROW(br11, ap11, L - 12)
  LROW(br12, ap12, L - 13) LROW(br13, ap13, L - 14) LROW(br14, ap14, L - 15)
  LROW(br15, ap15, L - 16)

  // one backtrack step at time TT_: BRa = best row tt (target), APb = alpha row tt-1.
  // ballot is provably nonzero (bitwise-exact recompute) -> tag = ffs-1 directly.
#define BSTEP(BRa, APb, TT_)                                   \
  {                                                            \
    const int tt = (TT_);                                      \
    float target = readlane_f((BRa), tag);                     \
    float tc = Tt[(tag << 6) | j];                             \
    unsigned long long m = __ballot((APb) + tc == target);     \
    tag = __ffsll((long long)m) - 1;                           \
    if (j == 0) ob[tt - 1] = tag;                              \
  }

  int tb = L - 1;
  // main: guard-free blocks of 16 (all steps tb..tb-15 >= 1)
  while (tb >= 16) {
    BSTEP(br0, ap1, tb - 0);   LROW(br0, ap0, tb - 16);
    BSTEP(br1, ap2, tb - 1);   LROW(br1, ap1, tb - 17);
    BSTEP(br2, ap3, tb - 2);   LROW(br2, ap2, tb - 18);
    BSTEP(br3, ap4, tb - 3);   LROW(br3, ap3, tb - 19);
    BSTEP(br4, ap5, tb - 4);   LROW(br4, ap4, tb - 20);
    BSTEP(br5, ap6, tb - 5);   LROW(br5, ap5, tb - 21);
    BSTEP(br6, ap7, tb - 6);   LROW(br6, ap6, tb - 22);
    BSTEP(br7, ap8, tb - 7);   LROW(br7, ap7, tb - 23);
    BSTEP(br8, ap9, tb - 8);   LROW(br8, ap8, tb - 24);
    BSTEP(br9, ap10, tb - 9);  LROW(br9, ap9, tb - 25);
    BSTEP(br10, ap11, tb - 10); LROW(br10, ap10, tb - 26);
    BSTEP(br11, ap12, tb - 11); LROW(br11, ap11, tb - 27);
    BSTEP(br12, ap13, tb - 12); LROW(br12, ap12, tb - 28);
    BSTEP(br13, ap14, tb - 13); LROW(br13, ap13, tb - 29);
    BSTEP(br14, ap15, tb - 14); LROW(br14, ap14, tb - 30);
    BSTEP(br15, ap0, tb - 15);  LROW(br15, ap15, tb - 31);
    tb -= 16;
  }
  // tail: tb in [0,15]; slot u holds row tb-u; ap slot u+1 holds row tb-u-1
  if (tb >= 1)  { BSTEP(br0, ap1, tb - 0); }
  if (tb >= 2)  { BSTEP(br1, ap2, tb - 1); }
  if (tb >= 3)  { BSTEP(br2, ap3, tb - 2); }
  if (tb >= 4)  { BSTEP(br3, ap4, tb - 3); }
  if (tb >= 5)  { BSTEP(br4, ap5, tb - 4); }
  if (tb >= 6)  { BSTEP(br5, ap6, tb - 5); }
  if (tb >= 7)  { BSTEP(br6, ap7, tb - 6); }
  if (tb >= 8)  { BSTEP(br7, ap8, tb - 7); }
  if (tb >= 9)  { BSTEP(br8, ap9, tb - 8); }
  if (tb >= 10) { BSTEP(br9, ap10, tb - 9); }
  if (tb >= 11) { BSTEP(br10, ap11, tb - 10); }
  if (tb >= 12) { BSTEP(br11, ap12, tb - 11); }
  if (tb >= 13) { BSTEP(br12, ap13, tb - 12); }
  if (tb >= 14) { BSTEP(br13, ap14, tb - 13); }
  if (tb >= 15) { BSTEP(br14, ap15, tb - 14); }
#undef BSTEP
#undef LROW

  // zero the padded tail t >= L
  for (int tt = L + j; tt < TT; tt += 64) ob[tt] = 0;
}

// ---- fallback (ws too small): proven single-kernel ----
__global__ __launch_bounds__(64, 1) void crf_fallback(const float* __restrict__ logits,
                                                      const int* __restrict__ lens,
                                                      const float* __restrict__ trans,
                                                      int* __restrict__ out) {
  const int b = blockIdx.x;
  const int j = threadIdx.x;
  const int jj = j < DD ? j : DD - 1;
  __shared__ unsigned char bp[TT * 64];

  float tcol[DD];
#pragma unroll
  for (int i = 0; i < DD; ++i) tcol[i] = trans[i * DD + jj];
  const float* lg = logits + (size_t)b * TT * DD;
  const int L = lens[b];
  float alpha = lg[jj];

  float e0 = lg[1 * DD + jj], e1 = lg[2 * DD + jj],
        e2 = lg[3 * DD + jj], e3 = lg[4 * DD + jj],
        e4 = lg[5 * DD + jj], e5 = lg[6 * DD + jj],
        e6 = lg[7 * DD + jj], e7 = lg[8 * DD + jj];

#define STEP(EV)                                                         \
  {                                                                      \
    float s_[DD];                                                        \
    _Pragma("unroll")                                                    \
    for (int i = 0; i < DD; ++i) s_[i] = readlane_f(alpha, i) + tcol[i]; \
    float best = vmax48(s_);                                             \
    int idx = argidx48(s_);                                              \
    alpha = best + (EV);                                                 \
    bp[t * 64 + j] = (unsigned char)idx;                                 \
  }
#define RELOAD(ES)                                 \
  {                                                \
    int r = t + PF; r = r > TT - 1 ? TT - 1 : r;   \
    ES = lg[r * DD + jj];                          \
  }
  int t = 1;
  while (t < L) {
    STEP(e0); RELOAD(e0); ++t; if (t >= L) break;
    STEP(e1); RELOAD(e1); ++t; if (t >= L) break;
    STEP(e2); RELOAD(e2); ++t; if (t >= L) break;
    STEP(e3); RELOAD(e3); ++t; if (t >= L) break;
    STEP(e4); RELOAD(e4); ++t; if (t >= L) break;
    STEP(e5); RELOAD(e5); ++t; if (t >= L) break;
    STEP(e6); RELOAD(e6); ++t; if (t >= L) break;
    STEP(e7); RELOAD(e7); ++t;
  }
#undef STEP
#undef RELOAD
  __syncthreads();

  float af[DD];
#pragma unroll
  for (int i = 0; i < DD; ++i) af[i] = readlane_f(alpha, i);
  int btag = argidx48(af);
  int* ob = out + (size_t)b * TT;
  if (j == 0) ob[L - 1] = btag;
  int H = j;
  for (int tt = L - 1; tt >= 1; --tt) {
    int v = bp[tt * 64 + jj];
    H = __shfl(v, H, 64);
    if (j == btag) ob[tt - 1] = H;
  }
  for (int tt = L + j; tt < TT; tt += 64) ob[tt] = 0;
}

extern "C" void kernel_launch(void* const* d_in, const int* in_sizes, int n_in,
                              void* d_out, int out_size, void* d_ws, size_t ws_size,
                              hipStream_t stream) {
  const float* logits = (const float*)d_in[0];
  const int* lens     = (const int*)d_in[1];
  const float* trans  = (const float*)d_in[2];
  int* out            = (int*)d_out;
  (void)in_sizes; (void)n_in; (void)out_size;

  if (ws_size >= WS_NEED) {
    float* aws = (float*)d_ws;
    crf_all<<<BB, 64, 0, stream>>>(logits, lens, trans, aws, out);
  } else {
    crf_fallback<<<BB, 64, 0, stream>>>(logits, lens, trans, out);
  }
}